// Round 6
// baseline (65.457 us; speedup 1.0000x reference)
//
#include <hip/hip_runtime.h>
#include <math.h>

// Problem constants (from reference setup_inputs)
#define N_NODES  2048
#define N_GRAPHS 128
#define NSUB     32
#define SSZ      10
#define NPAIRS   45
#define FEAT     96
#define HIDDEN   128
#define BN_EPS   1e-5f

#define NBLK     256   // 1 block/CU -> co-resident; 256 flags = 1 per thread
#define RPW      2     // rows per wave
#define ROWS_PB  8     // 4 waves * 2 rows

#define NTAIL    4     // blocks 0..3 run the tail, 32 graphs each

// ws float offsets
#define WS_C1    0
#define WS_C2    2048
#define WS_FLG0  4096                 // int[256]
#define WS_FLG1  (WS_FLG0 + 256)      // int[256]
#define WS_FLG2  (WS_FLG1 + 256)      // int[256]
#define WS_CG1   (WS_FLG2 + 256)      // float[128]
#define WS_CG2   (WS_CG1 + 128)
#define WS_CG3   (WS_CG2 + 128)
#define WS_ZBEG  WS_FLG0
#define WS_ZEND  (WS_CG3 + 128)

// Cache-bypassing relaxed atomics (coherence-point ops): cross-XCD visible
// with ZERO wbl2/inv cache maintenance (validated round 4: 167 -> 39 us).
__device__ __forceinline__ float aload(const float* p) {
    return __hip_atomic_load(const_cast<float*>(p), __ATOMIC_RELAXED, __HIP_MEMORY_SCOPE_AGENT);
}
__device__ __forceinline__ void astore(float* p, float v) {
    __hip_atomic_store(p, v, __ATOMIC_RELAXED, __HIP_MEMORY_SCOPE_AGENT);
}
__device__ __forceinline__ int aiload(int* p) {
    return __hip_atomic_load(p, __ATOMIC_RELAXED, __HIP_MEMORY_SCOPE_AGENT);
}
__device__ __forceinline__ void aistore(int* p, int v) {
    __hip_atomic_store(p, v, __ATOMIC_RELAXED, __HIP_MEMORY_SCOPE_AGENT);
}
__device__ __forceinline__ void afadd(float* p, float v) {
    __hip_atomic_fetch_add(p, v, __ATOMIC_RELAXED, __HIP_MEMORY_SCOPE_AGENT);
}

// Flat 1-hop grid barrier: __syncthreads() drains each wave's vmcnt (all
// coherence-point stores complete), one flag store per block, then EVERY
// thread polls exactly one flag (256 threads <-> 256 blocks). No gen hop.
__device__ __forceinline__ void flatbar(int* flg) {
    __syncthreads();
    if (threadIdx.x == 0) aistore(flg + blockIdx.x, 1);
    while (aiload(flg + threadIdx.x) == 0) __builtin_amdgcn_s_sleep(1);
    __syncthreads();
}

__global__ __launch_bounds__(256)
void rwgnn_persist(const float* __restrict__ adj,
                   const int*   __restrict__ gi,
                   const float* __restrict__ theta,
                   const float* __restrict__ gamma,
                   const float* __restrict__ beta,
                   const float* __restrict__ w1,
                   const float* __restrict__ b1,
                   const float* __restrict__ w2,
                   const float* __restrict__ b2,
                   float* __restrict__ out,
                   float* __restrict__ ws)
{
    __shared__ __align__(16) float c_lds[N_NODES];      // 8 KB: c1/c2 staging
    __shared__ float XR[N_GRAPHS][FEAT];                // 48 KB: tail only
    __shared__ float cnt_s[N_GRAPHS];
    __shared__ float Vl[3][NSUB];
    __shared__ float yl[3][N_GRAPHS];
    __shared__ float mv[6];
    __shared__ float afs[FEAT], bfs[FEAT];

    const int tid  = threadIdx.x;
    const int wv   = tid >> 6;
    const int lane = tid & 63;
    const int bid  = blockIdx.x;

    float* c1  = ws + WS_C1;
    float* c2  = ws + WS_C2;
    int* flg0  = (int*)(ws + WS_FLG0);
    int* flg1  = (int*)(ws + WS_FLG1);
    int* flg2  = (int*)(ws + WS_FLG2);
    float* C1g = ws + WS_CG1;
    float* C2g = ws + WS_CG2;
    float* C3g = ws + WS_CG3;

    const int r0 = bid * ROWS_PB + wv * RPW;

    // ---- P1: c1[row] = rowsum(A); C1g[g] += c1[row] ----
    #pragma unroll
    for (int r = 0; r < RPW; r++) {
        const float* Ar = adj + (size_t)(r0 + r) * N_NODES;
        float s = 0.f;
        #pragma unroll
        for (int c = lane * 4; c < N_NODES; c += 256) {
            float4 a = *reinterpret_cast<const float4*>(Ar + c);
            s += (a.x + a.y) + (a.z + a.w);
        }
        #pragma unroll
        for (int o = 32; o; o >>= 1) s += __shfl_down(s, o);
        if (lane == 0) { astore(&c1[r0 + r], s); afadd(&C1g[gi[r0 + r]], s); }
    }
    flatbar(flg0);

    // ---- P2: stage c1 -> LDS; c2[row] = A[row] . c1; C2g[g] += c2[row] ----
    #pragma unroll
    for (int k = 0; k < 8; k++) c_lds[k * 256 + tid] = aload(&c1[k * 256 + tid]);
    __syncthreads();
    #pragma unroll
    for (int r = 0; r < RPW; r++) {
        const float* Ar = adj + (size_t)(r0 + r) * N_NODES;
        float s = 0.f;
        #pragma unroll
        for (int c = lane * 4; c < N_NODES; c += 256) {
            float4 a = *reinterpret_cast<const float4*>(Ar + c);
            float4 x = *reinterpret_cast<const float4*>(&c_lds[c]);
            s += a.x * x.x + a.y * x.y + a.z * x.z + a.w * x.w;
        }
        #pragma unroll
        for (int o = 32; o; o >>= 1) s += __shfl_down(s, o);
        if (lane == 0) { astore(&c2[r0 + r], s); afadd(&C2g[gi[r0 + r]], s); }
    }
    flatbar(flg1);

    // ---- P3: stage c2 -> LDS; C3g[g] += A[row] . c2 ----
    #pragma unroll
    for (int k = 0; k < 8; k++) c_lds[k * 256 + tid] = aload(&c2[k * 256 + tid]);
    __syncthreads();
    #pragma unroll
    for (int r = 0; r < RPW; r++) {
        const float* Ar = adj + (size_t)(r0 + r) * N_NODES;
        float s = 0.f;
        #pragma unroll
        for (int c = lane * 4; c < N_NODES; c += 256) {
            float4 a = *reinterpret_cast<const float4*>(Ar + c);
            float4 x = *reinterpret_cast<const float4*>(&c_lds[c]);
            s += a.x * x.x + a.y * x.y + a.z * x.z + a.w * x.w;
        }
        #pragma unroll
        for (int o = 32; o; o >>= 1) s += __shfl_down(s, o);
        if (lane == 0) afadd(&C3g[gi[r0 + r]], s);
    }

    // post completion; non-tail blocks exit (no spin)
    __syncthreads();                     // drains vmcnt: my afadds are complete
    if (tid == 0) aistore(flg2 + bid, 1);
    if (bid >= NTAIL) return;

    // ---- Tail (blocks 0..3): sweep completion flags, then stats + BN + MLP
    //      for graphs [bid*32, bid*32+32) ----
    while (aiload(flg2 + tid) == 0) __builtin_amdgcn_s_sleep(1);
    __syncthreads();

    if (tid < N_GRAPHS) cnt_s[tid] = 0.f;
    __syncthreads();
    for (int n = tid; n < N_NODES; n += 256) atomicAdd(&cnt_s[gi[n]], 1.f);

    // V_i[s] = 1^T A_s^i 1 without materializing A_s
    if (tid < NSUB) {
        const float* th = theta + tid * NPAIRS;
        float u1[SSZ];
        #pragma unroll
        for (int k = 0; k < SSZ; k++) u1[k] = 0.f;
        float sumT = 0.f;
        #pragma unroll
        for (int i = 0; i < SSZ; i++) {
            #pragma unroll
            for (int j = i + 1; j < SSZ; j++) {
                const int p = i * (2 * SSZ - 1 - i) / 2 + (j - i - 1);
                float t = th[p]; t = t > 0.f ? t : 0.f;
                sumT += t; u1[i] += t; u1[j] += t;
            }
        }
        float V2 = 0.f;
        #pragma unroll
        for (int k = 0; k < SSZ; k++) V2 += u1[k] * u1[k];
        float V3 = 0.f;
        #pragma unroll
        for (int i = 0; i < SSZ; i++) {
            #pragma unroll
            for (int j = i + 1; j < SSZ; j++) {
                const int p = i * (2 * SSZ - 1 - i) / 2 + (j - i - 1);
                float t = th[p]; t = t > 0.f ? t : 0.f;
                V3 += t * u1[i] * u1[j];
            }
        }
        Vl[0][tid] = 2.f * sumT;
        Vl[1][tid] = V2;
        Vl[2][tid] = 2.f * V3;
    }
    __syncthreads();

    if (tid < N_GRAPHS) {
        float inv = 1.f / cnt_s[tid];
        yl[0][tid] = aload(&C1g[tid]) * inv;
        yl[1][tid] = aload(&C2g[tid]) * inv;
        yl[2][tid] = aload(&C3g[tid]) * inv;
    }
    __syncthreads();

    // batch mean/var over 128 graphs: wave i handles step i
    if (wv < 3) {
        float a = yl[wv][lane], b = yl[wv][lane + 64];
        float s = a + b;
        #pragma unroll
        for (int o = 32; o; o >>= 1) s += __shfl_xor(s, o);
        float m = s * (1.f / N_GRAPHS);
        float da = a - m, db = b - m;
        float v = da * da + db * db;
        #pragma unroll
        for (int o = 32; o; o >>= 1) v += __shfl_xor(v, o);
        v *= (1.f / N_GRAPHS);
        if (lane == 0) { mv[wv] = m; mv[3 + wv] = v; }
    }
    __syncthreads();

    // BN affine per feature: x[g,f] = afs[f]*y_i[g] + bfs[f]
    if (tid < FEAT) {
        int i = tid >> 5;
        float V = Vl[i][tid & 31];
        float scale = gamma[tid] * rsqrtf(V * V * mv[3 + i] + BN_EPS);
        afs[tid] = scale * V;
        bfs[tid] = beta[tid] - scale * V * mv[i];
    }
    __syncthreads();

    // materialize XR for all graphs (each tail block computes all; cheap)
    for (int idx = tid; idx < N_GRAPHS * FEAT; idx += 256) {
        int g = idx / FEAT, f = idx - g * FEAT;
        XR[g][f] = afs[f] * yl[f >> 5][g] + bfs[f];
    }
    __syncthreads();

    // MLP for my 32 graphs: wave wv does 8; lane l covers hidden l and l+64
    const float2 wa = *reinterpret_cast<const float2*>(w2 + 2 * lane);
    const float2 wb = *reinterpret_cast<const float2*>(w2 + 2 * (lane + 64));
    const float bb0 = b1[lane], bb1 = b1[lane + 64];
    for (int gg = 0; gg < 8; gg++) {
        const int g = bid * 32 + wv * 8 + gg;
        float acc0 = bb0, acc1 = bb1;
        #pragma unroll 8
        for (int f = 0; f < FEAT; f++) {
            float x = XR[g][f];
            acc0 = fmaf(x, w1[f * HIDDEN + lane], acc0);
            acc1 = fmaf(x, w1[f * HIDDEN + lane + 64], acc1);
        }
        float h0 = fmaxf(acc0, 0.f), h1 = fmaxf(acc1, 0.f);
        float p0 = h0 * wa.x + h1 * wb.x;
        float p1 = h0 * wa.y + h1 * wb.y;
        #pragma unroll
        for (int o = 32; o; o >>= 1) { p0 += __shfl_down(p0, o); p1 += __shfl_down(p1, o); }
        if (lane == 0) {
            out[2 * g + 0] = p0 + b2[0];
            out[2 * g + 1] = p1 + b2[1];
        }
    }
}

extern "C" void kernel_launch(void* const* d_in, const int* in_sizes, int n_in,
                              void* d_out, int out_size, void* d_ws, size_t ws_size,
                              hipStream_t stream) {
    const float* adj   = (const float*)d_in[0];
    const int*   gi    = (const int*)  d_in[1];
    const float* theta = (const float*)d_in[2];
    const float* gamma = (const float*)d_in[3];
    const float* beta  = (const float*)d_in[4];
    const float* w1    = (const float*)d_in[5];
    const float* b1    = (const float*)d_in[6];
    const float* w2    = (const float*)d_in[7];
    const float* b2    = (const float*)d_in[8];
    float* out = (float*)d_out;
    float* ws  = (float*)d_ws;

    // zero flags + C accumulators each call (graph-legal async memset, 4.6 KB)
    hipMemsetAsync((char*)d_ws + WS_ZBEG * sizeof(float), 0,
                   (WS_ZEND - WS_ZBEG) * sizeof(float), stream);

    rwgnn_persist<<<NBLK, 256, 0, stream>>>(adj, gi, theta, gamma, beta,
                                            w1, b1, w2, b2, out, ws);
}

// Round 7
// 51.463 us; speedup vs baseline: 1.2719x; 1.2719x over previous
//
#include <hip/hip_runtime.h>
#include <math.h>

// Problem constants (from reference setup_inputs)
#define N_NODES  2048
#define N_GRAPHS 128
#define NSUB     32
#define SSZ      10
#define NPAIRS   45
#define FEAT     96
#define HIDDEN   128
#define BN_EPS   1e-5f

#define NBLK     512   // 2 blocks/CU -> co-resident; R4-validated barrier scale
#define ROWS_PB  4     // 1 row per wave
#define MAXD     96    // sparse slots per row (mean degree 16; dense fallback if exceeded)

// ws float offsets
#define WS_C1    0
#define WS_C2    2048
#define WS_FLG   4096                  // int flags[3][512]
#define WS_GEN   (WS_FLG + 1536)       // int gen (padded to 8)
#define WS_CG1   (WS_GEN + 8)          // float C1g[128]
#define WS_CG2   (WS_CG1 + 128)
#define WS_CG3   (WS_CG2 + 128)
#define WS_ZBEG  WS_FLG
#define WS_ZEND  (WS_CG3 + 128)
#define WS_IDX   6144                          // int idx[2048][96]
#define WS_VAL   (WS_IDX + N_NODES * MAXD)     // float val[2048][96]
#define WS_DEG   (WS_VAL + N_NODES * MAXD)     // int deg[2048]

// Cache-bypassing relaxed atomics (coherence-point ops): cross-XCD visible
// with ZERO wbl2/inv cache maintenance (validated R4: 167 -> 39 us).
__device__ __forceinline__ float aload(const float* p) {
    return __hip_atomic_load(const_cast<float*>(p), __ATOMIC_RELAXED, __HIP_MEMORY_SCOPE_AGENT);
}
__device__ __forceinline__ void astore(float* p, float v) {
    __hip_atomic_store(p, v, __ATOMIC_RELAXED, __HIP_MEMORY_SCOPE_AGENT);
}
__device__ __forceinline__ int aiload(int* p) {
    return __hip_atomic_load(p, __ATOMIC_RELAXED, __HIP_MEMORY_SCOPE_AGENT);
}
__device__ __forceinline__ void aistore(int* p, int v) {
    __hip_atomic_store(p, v, __ATOMIC_RELAXED, __HIP_MEMORY_SCOPE_AGENT);
}
__device__ __forceinline__ void afadd(float* p, float v) {
    __hip_atomic_fetch_add(p, v, __ATOMIC_RELAXED, __HIP_MEMORY_SCOPE_AGENT);
}

// R4-validated barrier: ONE spinner per block (tid 0), block 0 sweeps flags
// with 256 threads then bumps gen. __syncthreads() drains vmcnt (all
// coherence-point stores complete) -> relaxed flag store is a valid release.
__device__ __forceinline__ void gbar(int* flags, int* gen, int phase) {
    __syncthreads();
    int* f = flags + (phase << 9);
    if (threadIdx.x == 0) aistore(f + blockIdx.x, 1);
    if (blockIdx.x == 0) {
        while (aiload(f + threadIdx.x) == 0) __builtin_amdgcn_s_sleep(2);
        while (aiload(f + threadIdx.x + 256) == 0) __builtin_amdgcn_s_sleep(2);
        __syncthreads();
        if (threadIdx.x == 0) aistore(gen, phase + 1);
    } else {
        if (threadIdx.x == 0) {
            while (aiload(gen) <= phase) __builtin_amdgcn_s_sleep(2);
        }
        __syncthreads();
    }
}

__global__ __launch_bounds__(256)
void rwgnn_persist(const float* __restrict__ adj,
                   const int*   __restrict__ gi,
                   const float* __restrict__ theta,
                   const float* __restrict__ gamma,
                   const float* __restrict__ beta,
                   const float* __restrict__ w1,
                   const float* __restrict__ b1,
                   const float* __restrict__ w2,
                   const float* __restrict__ b2,
                   float* __restrict__ out,
                   float* __restrict__ ws)
{
    __shared__ int nnzc[4];
    __shared__ float cnt_s[N_GRAPHS];
    __shared__ float Vl[3][NSUB];
    __shared__ float yl[3][N_GRAPHS];
    __shared__ float mv[6];
    __shared__ float xr[FEAT];
    __shared__ float red[4];

    const int tid  = threadIdx.x;
    const int wv   = tid >> 6;
    const int lane = tid & 63;
    const int bid  = blockIdx.x;

    float* c1  = ws + WS_C1;
    float* c2  = ws + WS_C2;
    int* flags = (int*)(ws + WS_FLG);
    int* gen   = (int*)(ws + WS_GEN);
    float* C1g = ws + WS_CG1;
    float* C2g = ws + WS_CG2;
    float* C3g = ws + WS_CG3;

    const int row = bid * ROWS_PB + wv;
    const float* Ar = adj + (size_t)row * N_NODES;
    int*   ridx = (int*)(ws + WS_IDX) + row * MAXD;   // block-local: plain cached
    float* rval = ws + WS_VAL + row * MAXD;
    int*   degp = (int*)(ws + WS_DEG);
    const int grow = gi[row];

    // ---- P1: c1[row] = rowsum(A); record sparse (idx,val) for this row ----
    if (lane == 0) nnzc[wv] = 0;
    __syncthreads();
    {
        float s = 0.f;
        for (int c = lane * 4; c < N_NODES; c += 256) {
            float4 a = *reinterpret_cast<const float4*>(Ar + c);
            s += (a.x + a.y) + (a.z + a.w);
            if (a.x != 0.f) { int p = atomicAdd(&nnzc[wv], 1); if (p < MAXD) { ridx[p] = c;     rval[p] = a.x; } }
            if (a.y != 0.f) { int p = atomicAdd(&nnzc[wv], 1); if (p < MAXD) { ridx[p] = c + 1; rval[p] = a.y; } }
            if (a.z != 0.f) { int p = atomicAdd(&nnzc[wv], 1); if (p < MAXD) { ridx[p] = c + 2; rval[p] = a.z; } }
            if (a.w != 0.f) { int p = atomicAdd(&nnzc[wv], 1); if (p < MAXD) { ridx[p] = c + 3; rval[p] = a.w; } }
        }
        #pragma unroll
        for (int o = 32; o; o >>= 1) s += __shfl_down(s, o);
        __syncthreads();           // all lanes' LDS atomics done before count read
        if (lane == 0) {
            astore(&c1[row], s);
            afadd(&C1g[grow], s);
            degp[row] = nnzc[wv];
        }
    }
    gbar(flags, gen, 0);

    // ---- P2: c2[row] = A[row].c1 via sparse gather (~16 uncached loads) ----
    {
        const int nz = degp[row];
        float s = 0.f;
        if (nz <= MAXD) {
            for (int k = lane; k < nz; k += 64)
                s += rval[k] * aload(&c1[ridx[k]]);
        } else {            // adversarial-density fallback: dense dot
            for (int c = lane; c < N_NODES; c += 64)
                s += Ar[c] * aload(&c1[c]);
        }
        #pragma unroll
        for (int o = 32; o; o >>= 1) s += __shfl_down(s, o);
        if (lane == 0) { astore(&c2[row], s); afadd(&C2g[grow], s); }
    }
    gbar(flags, gen, 1);

    // ---- P3: C3g[g] += A[row].c2 (c3 never materialized) ----
    {
        const int nz = degp[row];
        float s = 0.f;
        if (nz <= MAXD) {
            for (int k = lane; k < nz; k += 64)
                s += rval[k] * aload(&c2[ridx[k]]);
        } else {
            for (int c = lane; c < N_NODES; c += 64)
                s += Ar[c] * aload(&c2[c]);
        }
        #pragma unroll
        for (int o = 32; o; o >>= 1) s += __shfl_down(s, o);
        if (lane == 0) afadd(&C3g[grow], s);
    }

    // barrier 2: everyone posts arrival; only tail blocks (0..127) wait
    __syncthreads();                     // drain vmcnt: my afadds complete
    if (tid == 0) aistore(flags + (2 << 9) + bid, 1);
    if (bid >= N_GRAPHS) return;

    {
        int* f2 = flags + (2 << 9);
        if (bid == 0) {
            while (aiload(f2 + tid) == 0) __builtin_amdgcn_s_sleep(2);
            while (aiload(f2 + tid + 256) == 0) __builtin_amdgcn_s_sleep(2);
            __syncthreads();
            if (tid == 0) aistore(gen, 3);
        } else {
            if (tid == 0) {
                while (aiload(gen) <= 2) __builtin_amdgcn_s_sleep(2);
            }
            __syncthreads();
        }
    }

    // ---- Tail (blocks 0..127, redundant): stats + BN + MLP for graph g=bid ----
    const int g = bid;

    if (tid < N_GRAPHS) cnt_s[tid] = 0.f;
    __syncthreads();
    for (int n = tid; n < N_NODES; n += 256) atomicAdd(&cnt_s[gi[n]], 1.f);

    // V_i[s] = 1^T A_s^i 1 without materializing A_s
    if (tid < NSUB) {
        const float* th = theta + tid * NPAIRS;
        float u1[SSZ];
        #pragma unroll
        for (int k = 0; k < SSZ; k++) u1[k] = 0.f;
        float sumT = 0.f;
        #pragma unroll
        for (int i = 0; i < SSZ; i++) {
            #pragma unroll
            for (int j = i + 1; j < SSZ; j++) {
                const int p = i * (2 * SSZ - 1 - i) / 2 + (j - i - 1);
                float t = th[p]; t = t > 0.f ? t : 0.f;
                sumT += t; u1[i] += t; u1[j] += t;
            }
        }
        float V2 = 0.f;
        #pragma unroll
        for (int k = 0; k < SSZ; k++) V2 += u1[k] * u1[k];
        float V3 = 0.f;
        #pragma unroll
        for (int i = 0; i < SSZ; i++) {
            #pragma unroll
            for (int j = i + 1; j < SSZ; j++) {
                const int p = i * (2 * SSZ - 1 - i) / 2 + (j - i - 1);
                float t = th[p]; t = t > 0.f ? t : 0.f;
                V3 += t * u1[i] * u1[j];
            }
        }
        Vl[0][tid] = 2.f * sumT;
        Vl[1][tid] = V2;
        Vl[2][tid] = 2.f * V3;
    }
    __syncthreads();

    if (tid < N_GRAPHS) {
        float inv = 1.f / cnt_s[tid];
        yl[0][tid] = aload(&C1g[tid]) * inv;
        yl[1][tid] = aload(&C2g[tid]) * inv;
        yl[2][tid] = aload(&C3g[tid]) * inv;
    }
    __syncthreads();

    // batch mean/var over 128 graphs: wave i handles step i
    if (wv < 3) {
        float a = yl[wv][lane], b = yl[wv][lane + 64];
        float s = a + b;
        #pragma unroll
        for (int o = 32; o; o >>= 1) s += __shfl_xor(s, o);
        float m = s * (1.f / N_GRAPHS);
        float da = a - m, db = b - m;
        float v = da * da + db * db;
        #pragma unroll
        for (int o = 32; o; o >>= 1) v += __shfl_xor(v, o);
        v *= (1.f / N_GRAPHS);
        if (lane == 0) { mv[wv] = m; mv[3 + wv] = v; }
    }
    __syncthreads();

    if (tid < FEAT) {
        int i = tid >> 5;
        float V = Vl[i][tid & 31];
        float scale = gamma[tid] * rsqrtf(V * V * mv[3 + i] + BN_EPS);
        xr[tid] = scale * V * (yl[i][g] - mv[i]) + beta[tid];
    }
    __syncthreads();

    if (tid < HIDDEN) {
        float acc = b1[tid];
        #pragma unroll
        for (int f = 0; f < FEAT; f++)
            acc = fmaf(xr[f], w1[f * HIDDEN + tid], acc);
        float h = fmaxf(acc, 0.f);
        float2 w2v = *reinterpret_cast<const float2*>(w2 + 2 * tid);
        float p0 = h * w2v.x, p1 = h * w2v.y;
        #pragma unroll
        for (int o = 32; o; o >>= 1) { p0 += __shfl_down(p0, o); p1 += __shfl_down(p1, o); }
        int w = tid >> 6, l = tid & 63;
        if (l == 0) { red[2 * w] = p0; red[2 * w + 1] = p1; }
    }
    __syncthreads();
    if (tid == 0) {
        out[2 * g + 0] = red[0] + red[2] + b2[0];
        out[2 * g + 1] = red[1] + red[3] + b2[1];
    }
}

extern "C" void kernel_launch(void* const* d_in, const int* in_sizes, int n_in,
                              void* d_out, int out_size, void* d_ws, size_t ws_size,
                              hipStream_t stream) {
    const float* adj   = (const float*)d_in[0];
    const int*   gi    = (const int*)  d_in[1];
    const float* theta = (const float*)d_in[2];
    const float* gamma = (const float*)d_in[3];
    const float* beta  = (const float*)d_in[4];
    const float* w1    = (const float*)d_in[5];
    const float* b1    = (const float*)d_in[6];
    const float* w2    = (const float*)d_in[7];
    const float* b2    = (const float*)d_in[8];
    float* out = (float*)d_out;
    float* ws  = (float*)d_ws;

    // zero flags + gen + C accumulators each call (7.7 KB, graph-legal)
    hipMemsetAsync((char*)d_ws + WS_ZBEG * sizeof(float), 0,
                   (WS_ZEND - WS_ZBEG) * sizeof(float), stream);

    rwgnn_persist<<<NBLK, 256, 0, stream>>>(adj, gi, theta, gamma, beta,
                                            w1, b1, w2, b2, out, ws);
}

// Round 8
// 32.364 us; speedup vs baseline: 2.0225x; 1.5901x over previous
//
#include <hip/hip_runtime.h>
#include <math.h>

// Problem constants (from reference setup_inputs)
#define N_NODES  2048
#define N_GRAPHS 128
#define NSUB     32
#define SSZ      10
#define NPAIRS   45
#define FEAT     96
#define HIDDEN   128
#define BN_EPS   1e-5f

// ws float offsets
#define WS_C1 0
#define WS_C2 2048
#define WS_C3 4096

// ---- K1: c1[row] = rowsum(A). One wave per row, float4 coalesced. ----
__global__ __launch_bounds__(256) void k_rowsum(const float* __restrict__ A,
                                                float* __restrict__ c1) {
    const int row  = (blockIdx.x << 2) + (threadIdx.x >> 6);
    const int lane = threadIdx.x & 63;
    const float* Ar = A + (size_t)row * N_NODES;
    float s = 0.f;
    #pragma unroll
    for (int c = lane * 4; c < N_NODES; c += 256) {
        float4 a = *reinterpret_cast<const float4*>(Ar + c);
        s += (a.x + a.y) + (a.z + a.w);
    }
    #pragma unroll
    for (int o = 32; o; o >>= 1) s += __shfl_down(s, o);
    if (lane == 0) c1[row] = s;
}

// ---- K2/K3: y[row] = A[row] . x. Plain cached loads everywhere. ----
__global__ __launch_bounds__(256) void k_matvec(const float* __restrict__ A,
                                                const float* __restrict__ x,
                                                float* __restrict__ y) {
    const int row  = (blockIdx.x << 2) + (threadIdx.x >> 6);
    const int lane = threadIdx.x & 63;
    const float* Ar = A + (size_t)row * N_NODES;
    float s = 0.f;
    #pragma unroll
    for (int c = lane * 4; c < N_NODES; c += 256) {
        float4 a = *reinterpret_cast<const float4*>(Ar + c);
        float4 v = *reinterpret_cast<const float4*>(x + c);
        s += a.x * v.x + a.y * v.y + a.z * v.z + a.w * v.w;
    }
    #pragma unroll
    for (int o = 32; o; o >>= 1) s += __shfl_down(s, o);
    if (lane == 0) y[row] = s;
}

// ---- K4: 128 blocks; block g redundantly computes stats + BN, then the MLP
//      for its own graph. All reads plain cached (c1..c3 are 24 KB). ----
__global__ __launch_bounds__(256)
void k_tail(const int*   __restrict__ gi,
            const float* __restrict__ c1,
            const float* __restrict__ c2,
            const float* __restrict__ c3,
            const float* __restrict__ theta,
            const float* __restrict__ gamma,
            const float* __restrict__ beta,
            const float* __restrict__ w1,
            const float* __restrict__ b1,
            const float* __restrict__ w2,
            const float* __restrict__ b2,
            float* __restrict__ out) {
    __shared__ float cnt_s[N_GRAPHS];
    __shared__ float C[3][N_GRAPHS];
    __shared__ float Vl[3][NSUB];
    __shared__ float yl[3][N_GRAPHS];
    __shared__ float mv[6];
    __shared__ float xr[FEAT];
    __shared__ float red[4];

    const int tid  = threadIdx.x;
    const int wv   = tid >> 6;
    const int lane = tid & 63;
    const int g    = blockIdx.x;

    if (tid < N_GRAPHS) {
        cnt_s[tid] = 0.f; C[0][tid] = 0.f; C[1][tid] = 0.f; C[2][tid] = 0.f;
    }
    __syncthreads();

    // segment sums over nodes (coalesced cached reads, LDS atomics)
    for (int n = tid; n < N_NODES; n += 256) {
        const int gg = gi[n];
        atomicAdd(&cnt_s[gg], 1.f);
        atomicAdd(&C[0][gg], c1[n]);
        atomicAdd(&C[1][gg], c2[n]);
        atomicAdd(&C[2][gg], c3[n]);
    }

    // V_i[s] = 1^T A_s^i 1 without materializing A_s:
    //   u1 = A_s 1; V1 = 2*sum(t); V2 = ||u1||^2; V3 = 2*sum_p t_p u1[i_p] u1[j_p]
    if (tid < NSUB) {
        const float* th = theta + tid * NPAIRS;
        float u1[SSZ];
        #pragma unroll
        for (int k = 0; k < SSZ; k++) u1[k] = 0.f;
        float sumT = 0.f;
        #pragma unroll
        for (int i = 0; i < SSZ; i++) {
            #pragma unroll
            for (int j = i + 1; j < SSZ; j++) {
                const int p = i * (2 * SSZ - 1 - i) / 2 + (j - i - 1);
                float t = th[p]; t = t > 0.f ? t : 0.f;
                sumT += t; u1[i] += t; u1[j] += t;
            }
        }
        float V2 = 0.f;
        #pragma unroll
        for (int k = 0; k < SSZ; k++) V2 += u1[k] * u1[k];
        float V3 = 0.f;
        #pragma unroll
        for (int i = 0; i < SSZ; i++) {
            #pragma unroll
            for (int j = i + 1; j < SSZ; j++) {
                const int p = i * (2 * SSZ - 1 - i) / 2 + (j - i - 1);
                float t = th[p]; t = t > 0.f ? t : 0.f;
                V3 += t * u1[i] * u1[j];
            }
        }
        Vl[0][tid] = 2.f * sumT;
        Vl[1][tid] = V2;
        Vl[2][tid] = 2.f * V3;
    }
    __syncthreads();

    if (tid < N_GRAPHS) {
        float inv = 1.f / cnt_s[tid];
        yl[0][tid] = C[0][tid] * inv;
        yl[1][tid] = C[1][tid] * inv;
        yl[2][tid] = C[2][tid] * inv;
    }
    __syncthreads();

    // batch mean/var over 128 graphs: wave i handles step i
    if (wv < 3) {
        float a = yl[wv][lane], b = yl[wv][lane + 64];
        float s = a + b;
        #pragma unroll
        for (int o = 32; o; o >>= 1) s += __shfl_xor(s, o);
        float m = s * (1.f / N_GRAPHS);
        float da = a - m, db = b - m;
        float v = da * da + db * db;
        #pragma unroll
        for (int o = 32; o; o >>= 1) v += __shfl_xor(v, o);
        v *= (1.f / N_GRAPHS);
        if (lane == 0) { mv[wv] = m; mv[3 + wv] = v; }
    }
    __syncthreads();

    // normalized feature row for this block's graph
    if (tid < FEAT) {
        int i = tid >> 5;
        float V = Vl[i][tid & 31];
        float scale = gamma[tid] * rsqrtf(V * V * mv[3 + i] + BN_EPS);
        xr[tid] = scale * V * (yl[i][g] - mv[i]) + beta[tid];
    }
    __syncthreads();

    // MLP: h = relu(x @ w1 + b1); out = h @ w2 + b2
    if (tid < HIDDEN) {
        float acc = b1[tid];
        #pragma unroll
        for (int f = 0; f < FEAT; f++)
            acc = fmaf(xr[f], w1[f * HIDDEN + tid], acc);
        float h = fmaxf(acc, 0.f);
        float2 w2v = *reinterpret_cast<const float2*>(w2 + 2 * tid);
        float p0 = h * w2v.x, p1 = h * w2v.y;
        #pragma unroll
        for (int o = 32; o; o >>= 1) { p0 += __shfl_down(p0, o); p1 += __shfl_down(p1, o); }
        int w = tid >> 6, l = tid & 63;
        if (l == 0) { red[2 * w] = p0; red[2 * w + 1] = p1; }
    }
    __syncthreads();
    if (tid == 0) {
        out[2 * g + 0] = red[0] + red[2] + b2[0];
        out[2 * g + 1] = red[1] + red[3] + b2[1];
    }
}

extern "C" void kernel_launch(void* const* d_in, const int* in_sizes, int n_in,
                              void* d_out, int out_size, void* d_ws, size_t ws_size,
                              hipStream_t stream) {
    const float* adj   = (const float*)d_in[0];
    const int*   gi    = (const int*)  d_in[1];
    const float* theta = (const float*)d_in[2];
    const float* gamma = (const float*)d_in[3];
    const float* beta  = (const float*)d_in[4];
    const float* w1    = (const float*)d_in[5];
    const float* b1    = (const float*)d_in[6];
    const float* w2    = (const float*)d_in[7];
    const float* b2    = (const float*)d_in[8];
    float* out = (float*)d_out;
    float* ws  = (float*)d_ws;

    float* c1 = ws + WS_C1;
    float* c2 = ws + WS_C2;
    float* c3 = ws + WS_C3;

    // Stream-ordered dependency chain; kernel boundaries are the global sync.
    k_rowsum<<<512, 256, 0, stream>>>(adj, c1);
    k_matvec<<<512, 256, 0, stream>>>(adj, c1, c2);
    k_matvec<<<512, 256, 0, stream>>>(adj, c2, c3);
    k_tail  <<<N_GRAPHS, 256, 0, stream>>>(gi, c1, c2, c3, theta, gamma, beta,
                                           w1, b1, w2, b2, out);
}

// Round 9
// 32.236 us; speedup vs baseline: 2.0306x; 1.0040x over previous
//
#include <hip/hip_runtime.h>
#include <math.h>

// Problem constants (from reference setup_inputs)
#define N_NODES  2048
#define N_GRAPHS 128
#define NSUB     32
#define SSZ      10
#define NPAIRS   45
#define FEAT     96
#define HIDDEN   128
#define BN_EPS   1e-5f

#define MAXD     96    // sparse slots/row; mean degree 16, max ~40; dense fallback past this

// ws float offsets
#define WS_C1   0
#define WS_C2   2048
#define WS_C3   4096
#define WS_IDX  8192                        // int idx[2048][MAXD]
#define WS_VAL  (WS_IDX + N_NODES * MAXD)   // float val[2048][MAXD]
#define WS_DEG  (WS_VAL + N_NODES * MAXD)   // int deg[2048]

// ---- K1: c1[row] = rowsum(A); also build per-row sparse (idx,val). ----
__global__ __launch_bounds__(256) void k_rowsum_build(const float* __restrict__ A,
                                                      float* __restrict__ c1,
                                                      float* __restrict__ ws) {
    __shared__ int nnzc[4];
    const int wv   = threadIdx.x >> 6;
    const int lane = threadIdx.x & 63;
    const int row  = (blockIdx.x << 2) + wv;
    const float* Ar = A + (size_t)row * N_NODES;
    int*   ridx = (int*)(ws + WS_IDX) + row * MAXD;
    float* rval = ws + WS_VAL + row * MAXD;
    int*   degp = (int*)(ws + WS_DEG);

    if (lane == 0) nnzc[wv] = 0;
    __syncthreads();

    float s = 0.f;
    for (int c = lane * 4; c < N_NODES; c += 256) {
        float4 a = *reinterpret_cast<const float4*>(Ar + c);
        s += (a.x + a.y) + (a.z + a.w);
        if (a.x != 0.f) { int p = atomicAdd(&nnzc[wv], 1); if (p < MAXD) { ridx[p] = c;     rval[p] = a.x; } }
        if (a.y != 0.f) { int p = atomicAdd(&nnzc[wv], 1); if (p < MAXD) { ridx[p] = c + 1; rval[p] = a.y; } }
        if (a.z != 0.f) { int p = atomicAdd(&nnzc[wv], 1); if (p < MAXD) { ridx[p] = c + 2; rval[p] = a.z; } }
        if (a.w != 0.f) { int p = atomicAdd(&nnzc[wv], 1); if (p < MAXD) { ridx[p] = c + 3; rval[p] = a.w; } }
    }
    #pragma unroll
    for (int o = 32; o; o >>= 1) s += __shfl_down(s, o);
    __syncthreads();                     // all lanes' LDS atomics complete
    if (lane == 0) { c1[row] = s; degp[row] = nnzc[wv]; }
}

// ---- K2/K3: y[row] = A[row] . x via sparse gather (plain cached loads). ----
__global__ __launch_bounds__(256) void k_spmv(const float* __restrict__ A,
                                              const float* __restrict__ ws_ro,
                                              const float* __restrict__ x,
                                              float* __restrict__ y) {
    const int wv   = threadIdx.x >> 6;
    const int lane = threadIdx.x & 63;
    const int row  = (blockIdx.x << 2) + wv;
    const int nz   = ((const int*)(ws_ro + WS_DEG))[row];
    float s = 0.f;
    if (nz <= MAXD) {
        const int*   ridx = (const int*)(ws_ro + WS_IDX) + row * MAXD;
        const float* rval = ws_ro + WS_VAL + row * MAXD;
        for (int k = lane; k < nz; k += 64)
            s += rval[k] * x[ridx[k]];
    } else {                              // ultra-dense row fallback
        const float* Ar = A + (size_t)row * N_NODES;
        for (int c = lane * 4; c < N_NODES; c += 256) {
            float4 a = *reinterpret_cast<const float4*>(Ar + c);
            float4 v = *reinterpret_cast<const float4*>(x + c);
            s += a.x * v.x + a.y * v.y + a.z * v.z + a.w * v.w;
        }
    }
    #pragma unroll
    for (int o = 32; o; o >>= 1) s += __shfl_down(s, o);
    if (lane == 0) y[row] = s;
}

// ---- K4: 128 blocks; block g redundantly computes stats + BN, then the MLP
//      for its own graph. All reads plain cached (c1..c3 are 24 KB). ----
__global__ __launch_bounds__(256)
void k_tail(const int*   __restrict__ gi,
            const float* __restrict__ c1,
            const float* __restrict__ c2,
            const float* __restrict__ c3,
            const float* __restrict__ theta,
            const float* __restrict__ gamma,
            const float* __restrict__ beta,
            const float* __restrict__ w1,
            const float* __restrict__ b1,
            const float* __restrict__ w2,
            const float* __restrict__ b2,
            float* __restrict__ out) {
    __shared__ float cnt_s[N_GRAPHS];
    __shared__ float C[3][N_GRAPHS];
    __shared__ float Vl[3][NSUB];
    __shared__ float yl[3][N_GRAPHS];
    __shared__ float mv[6];
    __shared__ float xr[FEAT];
    __shared__ float red[4];

    const int tid  = threadIdx.x;
    const int wv   = tid >> 6;
    const int lane = tid & 63;
    const int g    = blockIdx.x;

    if (tid < N_GRAPHS) {
        cnt_s[tid] = 0.f; C[0][tid] = 0.f; C[1][tid] = 0.f; C[2][tid] = 0.f;
    }
    __syncthreads();

    for (int n = tid; n < N_NODES; n += 256) {
        const int gg = gi[n];
        atomicAdd(&cnt_s[gg], 1.f);
        atomicAdd(&C[0][gg], c1[n]);
        atomicAdd(&C[1][gg], c2[n]);
        atomicAdd(&C[2][gg], c3[n]);
    }

    // V_i[s] = 1^T A_s^i 1 without materializing A_s
    if (tid < NSUB) {
        const float* th = theta + tid * NPAIRS;
        float u1[SSZ];
        #pragma unroll
        for (int k = 0; k < SSZ; k++) u1[k] = 0.f;
        float sumT = 0.f;
        #pragma unroll
        for (int i = 0; i < SSZ; i++) {
            #pragma unroll
            for (int j = i + 1; j < SSZ; j++) {
                const int p = i * (2 * SSZ - 1 - i) / 2 + (j - i - 1);
                float t = th[p]; t = t > 0.f ? t : 0.f;
                sumT += t; u1[i] += t; u1[j] += t;
            }
        }
        float V2 = 0.f;
        #pragma unroll
        for (int k = 0; k < SSZ; k++) V2 += u1[k] * u1[k];
        float V3 = 0.f;
        #pragma unroll
        for (int i = 0; i < SSZ; i++) {
            #pragma unroll
            for (int j = i + 1; j < SSZ; j++) {
                const int p = i * (2 * SSZ - 1 - i) / 2 + (j - i - 1);
                float t = th[p]; t = t > 0.f ? t : 0.f;
                V3 += t * u1[i] * u1[j];
            }
        }
        Vl[0][tid] = 2.f * sumT;
        Vl[1][tid] = V2;
        Vl[2][tid] = 2.f * V3;
    }
    __syncthreads();

    if (tid < N_GRAPHS) {
        float inv = 1.f / cnt_s[tid];
        yl[0][tid] = C[0][tid] * inv;
        yl[1][tid] = C[1][tid] * inv;
        yl[2][tid] = C[2][tid] * inv;
    }
    __syncthreads();

    if (wv < 3) {
        float a = yl[wv][lane], b = yl[wv][lane + 64];
        float s = a + b;
        #pragma unroll
        for (int o = 32; o; o >>= 1) s += __shfl_xor(s, o);
        float m = s * (1.f / N_GRAPHS);
        float da = a - m, db = b - m;
        float v = da * da + db * db;
        #pragma unroll
        for (int o = 32; o; o >>= 1) v += __shfl_xor(v, o);
        v *= (1.f / N_GRAPHS);
        if (lane == 0) { mv[wv] = m; mv[3 + wv] = v; }
    }
    __syncthreads();

    if (tid < FEAT) {
        int i = tid >> 5;
        float V = Vl[i][tid & 31];
        float scale = gamma[tid] * rsqrtf(V * V * mv[3 + i] + BN_EPS);
        xr[tid] = scale * V * (yl[i][g] - mv[i]) + beta[tid];
    }
    __syncthreads();

    if (tid < HIDDEN) {
        float acc = b1[tid];
        #pragma unroll
        for (int f = 0; f < FEAT; f++)
            acc = fmaf(xr[f], w1[f * HIDDEN + tid], acc);
        float h = fmaxf(acc, 0.f);
        float2 w2v = *reinterpret_cast<const float2*>(w2 + 2 * tid);
        float p0 = h * w2v.x, p1 = h * w2v.y;
        #pragma unroll
        for (int o = 32; o; o >>= 1) { p0 += __shfl_down(p0, o); p1 += __shfl_down(p1, o); }
        int w = tid >> 6, l = tid & 63;
        if (l == 0) { red[2 * w] = p0; red[2 * w + 1] = p1; }
    }
    __syncthreads();
    if (tid == 0) {
        out[2 * g + 0] = red[0] + red[2] + b2[0];
        out[2 * g + 1] = red[1] + red[3] + b2[1];
    }
}

extern "C" void kernel_launch(void* const* d_in, const int* in_sizes, int n_in,
                              void* d_out, int out_size, void* d_ws, size_t ws_size,
                              hipStream_t stream) {
    const float* adj   = (const float*)d_in[0];
    const int*   gi    = (const int*)  d_in[1];
    const float* theta = (const float*)d_in[2];
    const float* gamma = (const float*)d_in[3];
    const float* beta  = (const float*)d_in[4];
    const float* w1    = (const float*)d_in[5];
    const float* b1    = (const float*)d_in[6];
    const float* w2    = (const float*)d_in[7];
    const float* b2    = (const float*)d_in[8];
    float* out = (float*)d_out;
    float* ws  = (float*)d_ws;

    float* c1 = ws + WS_C1;
    float* c2 = ws + WS_C2;
    float* c3 = ws + WS_C3;

    // Stream-ordered chain; kernel boundaries provide the global sync +
    // cross-XCD coherence (same mechanism c1/c2/c3 already depend on).
    k_rowsum_build<<<512, 256, 0, stream>>>(adj, c1, ws);
    k_spmv<<<512, 256, 0, stream>>>(adj, ws, c1, c2);
    k_spmv<<<512, 256, 0, stream>>>(adj, ws, c2, c3);
    k_tail<<<N_GRAPHS, 256, 0, stream>>>(gi, c1, c2, c3, theta, gamma, beta,
                                         w1, b1, w2, b2, out);
}